// Round 1
// baseline (156.188 us; speedup 1.0000x reference)
//
#include <hip/hip_runtime.h>
#include <math.h>

// TopKMoEGate: tokens T = B*S = 16384, D = 1024, E = 64, K = 2.
// Expert-per-lane design: lane e owns expert e (E == wavefront size == 64).
// Each wave accumulates 8 tokens' logits; w lane-private from LDS, x wave-uniform
// broadcast from LDS. Top-2 + sparse softmax fully in-wave via shfl_xor butterfly.

#define TPB_TOKENS 32       // tokens per block
#define TPW 8               // tokens per wave
#define BK 128              // k-chunk staged in LDS
#define NG (BK / 4)         // 32 float4 groups per chunk
#define DDIM 1024
#define NEXP 64

__global__ __launch_bounds__(256, 2)
void moe_gate_kernel(const float* __restrict__ x,
                     const float* __restrict__ gate_w,
                     const float* __restrict__ noise_weight,
                     const float* __restrict__ noise,
                     float* __restrict__ out_w,   // [T][64] fp32
                     float* __restrict__ out_i)   // [T][2] indices as fp32
{
    // w chunk: unit index = g*66 + e  (stride 66 units breaks write conflicts;
    // compute read at fixed g is 64 consecutive units across lanes -> conflict-free)
    __shared__ float4 ws4[NG * 66];                 // 33792 B
    // x chunk: unit index = t*33 + g (stride 33 units; reads are uniform/broadcast)
    __shared__ float4 xs4[TPB_TOKENS * 33];         // 16896 B

    const int tid  = threadIdx.x;
    const int lane = tid & 63;          // expert id
    const int wv   = tid >> 6;          // wave 0..3
    const int tokBase = blockIdx.x * TPB_TOKENS;

    float acc[TPW];
    #pragma unroll
    for (int t = 0; t < TPW; ++t) acc[t] = 0.f;

    const float nw = noise_weight[lane];

    // staging assignments
    const int w_g  = tid & 31;          // k-group for gate_w staging
    const int w_e0 = tid >> 5;          // 0..7 (+8r covers 64 experts)
    const int x_t  = tid >> 3;          // 0..31 token
    const int x_u0 = (tid & 7) * 4;     // unit base within row (32 units/row)

    for (int c = 0; c < DDIM / BK; ++c) {
        const int k0 = c * BK;
        __syncthreads();
        // stage gate_w chunk: 8 rows per thread, coalesced (512B segments)
        #pragma unroll
        for (int r = 0; r < 8; ++r) {
            const int e = w_e0 + 8 * r;
            const float4 v = *(const float4*)&gate_w[e * DDIM + k0 + w_g * 4];
            ws4[w_g * 66 + e] = v;
        }
        // stage x chunk: 4 units per thread
        #pragma unroll
        for (int r = 0; r < 4; ++r) {
            const int u = x_u0 + r;
            const float4 v = *(const float4*)&x[(size_t)(tokBase + x_t) * DDIM + k0 + u * 4];
            xs4[x_t * 33 + u] = v;
        }
        __syncthreads();
        // compute: per g: 1 private w read + 8 uniform x reads + 32 FMAs
        for (int g = 0; g < NG; ++g) {
            const float4 w4 = ws4[g * 66 + lane];
            #pragma unroll
            for (int t = 0; t < TPW; ++t) {
                const float4 x4 = xs4[(wv * TPW + t) * 33 + g];
                acc[t] = fmaf(w4.x, x4.x, acc[t]);
                acc[t] = fmaf(w4.y, x4.y, acc[t]);
                acc[t] = fmaf(w4.z, x4.z, acc[t]);
                acc[t] = fmaf(w4.w, x4.w, acc[t]);
            }
        }
    }

    // epilogue: noise, top-2, sparse softmax, store
    #pragma unroll
    for (int t = 0; t < TPW; ++t) {
        const int tok = tokBase + wv * TPW + t;
        const float ln = fmaf(noise[(size_t)tok * NEXP + lane], nw, acc[t]);

        // top-1 (ties -> lower index, matching jax.lax.top_k)
        float v1 = ln; int i1 = lane;
        #pragma unroll
        for (int off = 32; off > 0; off >>= 1) {
            const float vo = __shfl_xor(v1, off, 64);
            const int   io = __shfl_xor(i1, off, 64);
            if (vo > v1 || (vo == v1 && io < i1)) { v1 = vo; i1 = io; }
        }
        // top-2: exclude i1
        float v2 = (lane == i1) ? -3.4e38f : ln; int i2 = lane;
        #pragma unroll
        for (int off = 32; off > 0; off >>= 1) {
            const float vo = __shfl_xor(v2, off, 64);
            const int   io = __shfl_xor(i2, off, 64);
            if (vo > v2 || (vo == v2 && io < i2)) { v2 = vo; i2 = io; }
        }

        const float d   = expf(v2 - v1);       // exp(l2 - l1) <= 1
        const float inv = 1.f / (1.f + d);
        const float wgt = (lane == i1) ? inv : ((lane == i2) ? d * inv : 0.f);
        out_w[(size_t)tok * NEXP + lane] = wgt;
        if (lane == 0) {
            out_i[(size_t)tok * 2]     = (float)i1;
            out_i[(size_t)tok * 2 + 1] = (float)i2;
        }
    }
}

extern "C" void kernel_launch(void* const* d_in, const int* in_sizes, int n_in,
                              void* d_out, int out_size, void* d_ws, size_t ws_size,
                              hipStream_t stream) {
    const float* x     = (const float*)d_in[0];
    const float* gw    = (const float*)d_in[1];
    const float* nwt   = (const float*)d_in[2];
    const float* noise = (const float*)d_in[3];
    const int T = in_sizes[0] / DDIM;           // 16384 tokens
    float* out_w = (float*)d_out;               // [T][64]
    float* out_i = (float*)d_out + (size_t)T * NEXP;  // [T][2] as float
    const int blocks = T / TPB_TOKENS;          // 512
    hipLaunchKernelGGL(moe_gate_kernel, dim3(blocks), dim3(256), 0, stream,
                       x, gw, nwt, noise, out_w, out_i);
}